// Round 15
// baseline (9549.814 us; speedup 1.0000x reference)
//
#include <hip/hip_runtime.h>
#include <hip/hip_bf16.h>
#include <stdint.h>

#define KKTOT 100000
#define BAP   2048
#define KPADMAX 100352   // 49*2048
#define NBLK  256        // chain grid: 256 blocks x 68KB LDS -> guaranteed co-resident (cap 512)

typedef _Float16 f16x8 __attribute__((ext_vector_type(8)));
typedef float    f32x4 __attribute__((ext_vector_type(4)));

// ---- constants (match reference f32 arithmetic) ----
__device__ __constant__ float KCf  = (float)(4.0 * 3.14159265358979323846 * 77.0e9 / 299792458.0);
__device__ __constant__ float I2PA = (float)(0.15915494309189534940823);
__device__ __constant__ float I2PB = (float)(0.15915494309189534940823 - (double)(float)(0.15915494309189534940823));

__device__ __forceinline__ float phase_frac(float dy, float dxx) {
    float d2 = fmaf(dy, dy, fmaf(dxx, dxx, 0.09f));
    float ph = KCf * sqrtf(d2);
    float h  = ph * I2PA;
    float l  = fmaf(ph, I2PA, -h);
    l = fmaf(ph, I2PB, l);
    return (h - floorf(h)) + l;                  // revolutions
}

__device__ __forceinline__ void gload16(const void* g, void* l) {
    __builtin_amdgcn_global_load_lds(
        (__attribute__((address_space(1))) void*)(uintptr_t)g,
        (__attribute__((address_space(3))) void*)(uint32_t)(uintptr_t)l,
        16, 0, 0);
}

__device__ __forceinline__ float2 cmulf(float2 a, float2 b) {
    return make_float2(a.x*b.x - a.y*b.y, a.x*b.y + a.y*b.x);
}

// ---- manual grid barrier: device-scope atomics (cross-XCD coherent), release/acquire fences ----
__device__ __forceinline__ void grid_barrier(int* __restrict__ bar) {
    __syncthreads();
    __threadfence();                                     // release: wbL2 + drain
    if (threadIdx.x == 0) {
        int gen = atomicAdd(&bar[1], 0);                 // read generation BEFORE arrival
        int t = atomicAdd(&bar[0], 1);
        if (t == NBLK - 1) {
            atomicExch(&bar[0], 0);                      // all arrived; reset for next gen
            atomicAdd(&bar[1], 1);                       // open the gate
        } else {
            while (atomicAdd(&bar[1], 0) == gen) __builtin_amdgcn_s_sleep(2);
        }
    }
    __syncthreads();
    __threadfence();                                     // acquire: invalidate L1/L2
}

// ---------------- decode py (int32) ----------------
__global__ __launch_bounds__(256) void decode_k(const float* __restrict__ sar, const int* __restrict__ py,
                                                float* __restrict__ ay, float* __restrict__ ax, float* __restrict__ rd) {
    int i = blockIdx.x * 256 + threadIdx.x;
    if (i >= KKTOT) return;
    int p = py[i];
    int iy = p & 511, ix = p >> 9;
    ay[i] = ((float)iy + 0.5f - 256.0f) * 1e-3f;
    ax[i] = ((float)ix + 0.5f - 256.0f) * 1e-3f;
    rd[i] = sar[p];
}

// ---------------- generate C=cos, S=sin as f16, layout [2048][Kc] ----------------
__global__ __launch_bounds__(256) void gen_cs(_Float16* __restrict__ C, _Float16* __restrict__ S,
                                              const float* __restrict__ ay, const float* __restrict__ ax,
                                              int k0, int Kc) {
    int j = blockIdx.y;
    long long kk = ((long long)blockIdx.x * 256 + threadIdx.x) * 8;
    size_t o = (size_t)j * Kc + kk;
    long long kg = (long long)k0 + kk;
    f16x8 cv, sv;
    if (j < 2000 && kg < KKTOT) {
        int jy = j % 40, jx = j / 40;
        float why = ((float)jy * (200.0f/39.0f) - 100.0f) * 1e-3f;   // wh2[jy]
        float whx = ((float)jx * (200.0f/49.0f) - 100.0f) * 1e-3f;   // wh1[jx]
        float4 a0 = *(const float4*)(ay + kg);
        float4 a1 = *(const float4*)(ay + kg + 4);
        float4 b0 = *(const float4*)(ax + kg);
        float4 b1 = *(const float4*)(ax + kg + 4);
        float ayv[8] = {a0.x,a0.y,a0.z,a0.w,a1.x,a1.y,a1.z,a1.w};
        float axv[8] = {b0.x,b0.y,b0.z,b0.w,b1.x,b1.y,b1.z,b1.w};
        #pragma unroll
        for (int e = 0; e < 8; ++e) {
            float fr = phase_frac(ayv[e]-why, axv[e]-whx);
            cv[e] = (_Float16)__builtin_amdgcn_cosf(fr);
            sv[e] = (_Float16)__builtin_amdgcn_sinf(fr);
        }
    } else {
        #pragma unroll
        for (int e = 0; e < 8; ++e) { cv[e] = (_Float16)0.f; sv[e] = (_Float16)0.f; }
    }
    *(f16x8*)(C + o) = cv;
    *(f16x8*)(S + o) = sv;
}

// ---------------- UPPER-TRIANGLE fused Gram GEMM (compact grid, z=16, atomic epilogue) ----------------
__global__ __launch_bounds__(256) void gemm_ut(const _Float16* __restrict__ C, const _Float16* __restrict__ S,
                                               float* __restrict__ R, float* __restrict__ Pm,
                                               int kiters, int kstride) {
    int rem = blockIdx.x;
    int mi = 0;
    #pragma unroll
    for (int r = 0; r < 16; ++r) {
        int cnt = 16 - r;
        if (rem < cnt) { mi = r; break; }
        rem -= cnt;
    }
    const int ni = mi + rem;
    const int z = blockIdx.y;

    __shared__ _Float16 ldsCa[8192];
    __shared__ _Float16 ldsSa[8192];
    __shared__ _Float16 ldsCb[8192];
    __shared__ _Float16 ldsSb[8192];
    const int t = threadIdx.x;
    const int w = t >> 6;
    const int lane = t & 63;

    f32x4 accR[4][4], accP[4][4];
    #pragma unroll
    for (int a = 0; a < 4; ++a)
        #pragma unroll
        for (int b = 0; b < 4; ++b) { accR[a][b] = (f32x4){0.f,0.f,0.f,0.f}; accP[a][b] = (f32x4){0.f,0.f,0.f,0.f}; }

    size_t aoff[4], boff[4];
    #pragma unroll
    for (int r = 0; r < 4; ++r) {
        int c = r * 256 + t;
        int jl = c >> 3;
        int ks = (c & 7) ^ (jl & 7);
        aoff[r] = (size_t)(mi*128 + jl) * kstride + ks*8;
        boff[r] = (size_t)(ni*128 + jl) * kstride + ks*8;
    }
    const int wm = w & 1, wn = w >> 1;
    const int q = lane >> 4, lm = lane & 15;
    const int ajl = wm*64 + lm;
    const int aoffl = (ajl*8 + (q ^ (ajl & 7))) * 16;
    const int bjl = wn*64 + lm;
    const int boffl = (bjl*8 + (q ^ (bjl & 7))) * 16;

    const int kq = kiters >> 4;
    for (int kt = z*kq; kt < (z+1)*kq; ++kt) {
        __syncthreads();
        const _Float16* gc = C + (size_t)kt * 64;
        const _Float16* gs = S + (size_t)kt * 64;
        #pragma unroll
        for (int r = 0; r < 4; ++r) {
            size_t dst = (size_t)(r*256 + w*64)*16;
            gload16(gc + aoff[r], (char*)ldsCa + dst);
            gload16(gs + aoff[r], (char*)ldsSa + dst);
            gload16(gc + boff[r], (char*)ldsCb + dst);
            gload16(gs + boff[r], (char*)ldsSb + dst);
        }
        __syncthreads();
        #pragma unroll
        for (int ks = 0; ks < 2; ++ks) {
            f16x8 bfC[4], bfS[4];
            #pragma unroll
            for (int nt = 0; nt < 4; ++nt) {
                bfC[nt] = *(const f16x8*)((const char*)ldsCb + ((boffl ^ (ks*64)) + nt*2048));
                bfS[nt] = *(const f16x8*)((const char*)ldsSb + ((boffl ^ (ks*64)) + nt*2048));
            }
            #pragma unroll
            for (int mt = 0; mt < 4; ++mt) {
                f16x8 afC = *(const f16x8*)((const char*)ldsCa + ((aoffl ^ (ks*64)) + mt*2048));
                f16x8 afS = *(const f16x8*)((const char*)ldsSa + ((aoffl ^ (ks*64)) + mt*2048));
                f16x8 nfS;
                #pragma unroll
                for (int e = 0; e < 8; ++e) nfS[e] = -afS[e];
                #pragma unroll
                for (int nt = 0; nt < 4; ++nt) {
                    accR[mt][nt] = __builtin_amdgcn_mfma_f32_16x16x32_f16(afC, bfC[nt], accR[mt][nt], 0, 0, 0);
                    accR[mt][nt] = __builtin_amdgcn_mfma_f32_16x16x32_f16(afS, bfS[nt], accR[mt][nt], 0, 0, 0);
                    accP[mt][nt] = __builtin_amdgcn_mfma_f32_16x16x32_f16(afC, bfS[nt], accP[mt][nt], 0, 0, 0);
                    accP[mt][nt] = __builtin_amdgcn_mfma_f32_16x16x32_f16(nfS, bfC[nt], accP[mt][nt], 0, 0, 0);
                }
            }
        }
    }
    #pragma unroll
    for (int mt = 0; mt < 4; ++mt) {
        #pragma unroll
        for (int nt = 0; nt < 4; ++nt) {
            int row0 = mi*128 + wm*64 + mt*16 + q*4;
            int col  = ni*128 + wn*64 + nt*16 + lm;
            float* rp = R  + (size_t)row0 * BAP + col;
            float* pp = Pm + (size_t)row0 * BAP + col;
            #pragma unroll
            for (int rr = 0; rr < 4; ++rr) {
                atomicAdd(rp + (size_t)rr * BAP, accR[mt][nt][rr]);
                atomicAdd(pp + (size_t)rr * BAP, accP[mt][nt][rr]);
            }
        }
    }
}

// ---------------- xd = DI * Hp^H rd ----------------
__global__ __launch_bounds__(256) void xd_init(const float* __restrict__ ay, const float* __restrict__ ax,
                                               const float* __restrict__ rd, float2* __restrict__ xd) {
    int j = blockIdx.x;
    int t = threadIdx.x;
    __shared__ float redr[256], redi[256];
    if (j >= 2000) { if (t == 0) xd[j] = make_float2(0.f, 0.f); return; }
    int jy = j % 40, jx = j / 40;
    float why = ((float)jy * (200.0f/39.0f) - 100.0f) * 1e-3f;
    float whx = ((float)jx * (200.0f/49.0f) - 100.0f) * 1e-3f;
    float sr = 0.f, si = 0.f;
    for (int i = t; i < KKTOT; i += 256) {
        float fr = phase_frac(ay[i]-why, ax[i]-whx);
        float r = rd[i];
        sr = fmaf(r, __builtin_amdgcn_cosf(fr), sr);
        si = fmaf(r, __builtin_amdgcn_sinf(fr), si);
    }
    redr[t] = sr; redi[t] = si;
    __syncthreads();
    for (int s2 = 128; s2 > 0; s2 >>= 1) {
        if (t < s2) { redr[t] += redr[t+s2]; redi[t] += redi[t+s2]; }
        __syncthreads();
    }
    if (t == 0) xd[j] = make_float2(0.01f * redr[0], -0.01f * redi[0]);
}

// ---------------- build G from upper-tri planes, Hermitian mirror ----------------
__global__ __launch_bounds__(256) void build_G_tile(const float* __restrict__ R, const float* __restrict__ Pm,
                                                    float2* __restrict__ G) {
    int ti = blockIdx.y, tj = blockIdx.x;
    if (tj < ti) return;
    __shared__ float2 tile[64][65];
    int t = threadIdx.x;
    #pragma unroll
    for (int r = 0; r < 16; ++r) {
        int e = t + 256*r;
        int lr = e >> 6, lc = e & 63;
        size_t mn = (size_t)(ti*64 + lr) * BAP + tj*64 + lc;
        float re = 0.01f * R[mn];
        float im = 0.01f * Pm[mn];
        G[mn] = make_float2(re, im);
        tile[lc][lr] = make_float2(re, -im);
    }
    if (tj == ti) return;
    __syncthreads();
    #pragma unroll
    for (int r = 0; r < 16; ++r) {
        int e = t + 256*r;
        int lr = e >> 6, lc = e & 63;
        G[(size_t)(tj*64 + lr) * BAP + ti*64 + lc] = tile[lr][lc];
    }
}

// ---------------- FUSED panel chain (manual grid barrier, normal launch) ----------------
__global__ __launch_bounds__(256) void chain_k(float2* __restrict__ G, float2* __restrict__ xd,
                                               float2* __restrict__ T, float2* __restrict__ Vp,
                                               float2* __restrict__ vvv, float* __restrict__ sarr,
                                               int* __restrict__ bar) {
    __shared__ __align__(16) char smem[69632];   // 68 KB union of the three stage layouts
    const int bid = blockIdx.x;
    const int t = threadIdx.x;
    const int i = t & 63, wg = t >> 6;

    for (int p = 0; p < 32; ++p) {
        const int p0 = p * 64;
        // ======== stage F: blocked panel factorization + V=U^-1 (block 0 only) ========
        if (bid == 0) {
            float2* Rcm   = (float2*)smem;           // [64*65]
            float2* Vcm   = Rcm + 64*65;             // [64*65]
            float2* xdp   = Vcm + 64*65;             // [64]
            float2* dinvv = xdp + 64;                // [64]
            #pragma unroll
            for (int r = 0; r < 16; ++r) {
                int e = t + 256*r;
                int ci = e & 63, ri = e >> 6;
                Rcm[ci*65 + ri] = G[(size_t)(p0+ri)*BAP + p0 + ci];
            }
            #pragma unroll
            for (int r = 0; r < 17; ++r) {
                int e = t + 256*r;
                if (e < 64*65) Vcm[e] = make_float2(0.f, 0.f);
            }
            if (wg == 0) xdp[i] = xd[p0 + i];
            __syncthreads();
            for (int sub = 0; sub < 4; ++sub) {
                int cS = sub*16 + wg*4;
                float2 raccR[4], raccV[4];
                #pragma unroll
                for (int u = 0; u < 4; ++u) {
                    raccR[u] = Rcm[(cS+u)*65 + i];
                    raccV[u] = Vcm[(cS+u)*65 + i];
                }
                for (int j = 0; j < sub*16; ++j) {
                    float2 dv = dinvv[j];
                    float2 colji = Rcm[j*65 + i];
                    float2 tj = cmulf(colji, dv);
                    float2 vji = Vcm[j*65 + i];
                    #pragma unroll
                    for (int u = 0; u < 4; ++u) {
                        float2 x = Rcm[j*65 + cS + u];
                        float2 rv = make_float2(x.x, -x.y);
                        raccR[u].x -= tj.x*rv.x - tj.y*rv.y;
                        raccR[u].y -= tj.x*rv.y + tj.y*rv.x;
                        raccV[u].x += vji.x*rv.x - vji.y*rv.y;
                        raccV[u].y += vji.x*rv.y + vji.y*rv.x;
                    }
                }
                #pragma unroll
                for (int u = 0; u < 4; ++u) {
                    Rcm[(cS+u)*65 + i] = raccR[u];
                    Vcm[(cS+u)*65 + i] = raccV[u];
                }
                __syncthreads();
                for (int jj = 0; jj < 16; ++jj) {
                    int j = sub*16 + jj;
                    float2 pr = Rcm[j*65 + j];
                    float dr = 1.0f + pr.x, dii = pr.y;
                    float idn = 1.0f / (dr*dr + dii*dii);
                    float2 dv = make_float2(dr*idn, -dii*idn);
                    float2 colv = Rcm[j*65 + i];
                    float2 tp = cmulf(colv, dv);
                    float2 mv = Vcm[j*65 + i];
                    float2 Vij = cmulf(make_float2((i==j ? 1.0f : 0.0f) - mv.x, -mv.y), dv);
                    float2 vj = xdp[j];
                    float2 rowv[4];
                    #pragma unroll
                    for (int u = 0; u < 4; ++u) {
                        float2 x = Rcm[j*65 + cS + u];
                        rowv[u] = make_float2(x.x, -x.y);
                    }
                    __syncthreads();
                    if (wg == 0) {
                        Vcm[j*65 + i] = Vij;
                        float2 xi = xdp[i];
                        xi.x -= tp.x*vj.x - tp.y*vj.y;
                        xi.y -= tp.x*vj.y + tp.y*vj.x;
                        xdp[i] = xi;
                    }
                    if (t == j) { dinvv[j] = dv; vvv[j] = vj; sarr[j] = dr; }
                    #pragma unroll
                    for (int u = 0; u < 4; ++u) {
                        int c = cS + u;
                        if (c > j) {
                            float2 rv = rowv[u];
                            float2 cur = Rcm[c*65 + i];
                            cur.x -= tp.x*rv.x - tp.y*rv.y;
                            cur.y -= tp.x*rv.y + tp.y*rv.x;
                            Rcm[c*65 + i] = cur;
                            float2 m = Vcm[c*65 + i];
                            m.x += Vij.x*rv.x - Vij.y*rv.y;
                            m.y += Vij.x*rv.y + Vij.y*rv.x;
                            Vcm[c*65 + i] = m;
                        }
                    }
                    __syncthreads();
                }
            }
            #pragma unroll
            for (int r = 0; r < 16; ++r) {
                int e = t + 256*r;
                int ri = e >> 6, ci = e & 63;
                Vp[e] = Vcm[ci*65 + ri];
            }
        }
        grid_barrier(bar);
        // ======== stage T: dense T = src·V + xd -= T·v (32 r-tiles, strided) ========
        for (int rt = bid; rt < 32; rt += NBLK) {
            float*  srcRe = (float*)smem;            // [64*64]
            float*  srcIm = srcRe + 4096;            // [64*64]
            float2* Vb    = (float2*)(srcIm + 4096); // [64*64]
            float2* vb    = Vb + 4096;               // [64]
            float2* xred  = vb + 64;                 // [4*64]
            int r = rt * 64 + i;
            {
                const float2* gp = G + (size_t)r * BAP + p0 + wg*16;
                #pragma unroll
                for (int k = 0; k < 16; ++k) {
                    float2 g = gp[k];
                    srcRe[(wg*16 + k)*64 + i] = g.x;
                    srcIm[(wg*16 + k)*64 + i] = g.y;
                }
            }
            #pragma unroll
            for (int q = 0; q < 16; ++q) {
                int e = t + 256*q;
                Vb[e] = Vp[e];
            }
            if (wg == 0) vb[i] = vvv[i];
            __syncthreads();
            int jb = wg * 16;
            float2 acc[16];
            #pragma unroll
            for (int jj = 0; jj < 16; ++jj) acc[jj] = make_float2(0.f, 0.f);
            for (int k = 0; k < 64; ++k) {
                float sx = srcRe[k*64 + i];
                float sy = srcIm[k*64 + i];
                #pragma unroll
                for (int jj = 0; jj < 16; ++jj) {
                    float2 vk = Vb[k*64 + jb + jj];
                    acc[jj].x = fmaf(sx, vk.x, fmaf(-sy, vk.y, acc[jj].x));
                    acc[jj].y = fmaf(sx, vk.y, fmaf( sy, vk.x, acc[jj].y));
                }
            }
            float2 xp = make_float2(0.f, 0.f);
            #pragma unroll
            for (int jj = 0; jj < 16; ++jj) {
                T[(size_t)(jb + jj) * BAP + r] = acc[jj];
                float2 vj = vb[jb + jj];
                xp.x += acc[jj].x*vj.x - acc[jj].y*vj.y;
                xp.y += acc[jj].x*vj.y + acc[jj].y*vj.x;
            }
            xred[wg*64 + i] = xp;
            __syncthreads();
            if (wg == 0) {
                float2 x = xd[r];
                #pragma unroll
                for (int g2 = 0; g2 < 4; ++g2) { x.x -= xred[g2*64 + i].x; x.y -= xred[g2*64 + i].y; }
                xd[r] = x;
            }
            __syncthreads();
        }
        grid_barrier(bar);
        // ======== stage U: trailing (future cols) + diag fix (past+current diags), strided ========
        {
            int nct = (31 - p) * 16;
            for (int wk = bid; wk < nct + 16; wk += NBLK) {
                if (wk < nct) {
                    float2* Tb = (float2*)smem;      // [16*128]
                    float2* Wb = Tb + 16*128;        // [16*64]
                    int cidx = wk >> 4, ridx = wk & 15;
                    int cx = (p + 1 + cidx) * 64, ry = ridx * 128;
                    int rq = t >> 4, cq = t & 15;
                    float2 acc[8][4];
                    #pragma unroll
                    for (int si = 0; si < 8; ++si)
                        #pragma unroll
                        for (int u = 0; u < 4; ++u) acc[si][u] = make_float2(0.f, 0.f);
                    for (int k0 = 0; k0 < 64; k0 += 16) {
                        __syncthreads();
                        #pragma unroll
                        for (int r = 0; r < 4; ++r) {
                            int e = t + 256*r;
                            int k = e >> 6, x4 = e & 63;
                            *(float4*)&Tb[k*128 + x4*2] = *(const float4*)(T + (size_t)(k0+k) * BAP + ry + x4*2);
                        }
                        #pragma unroll
                        for (int r = 0; r < 2; ++r) {
                            int e = t + 256*r;
                            int k = e >> 5, x4 = e & 31;
                            float sk = sarr[k0+k];
                            float4 tv = *(const float4*)(T + (size_t)(k0+k) * BAP + cx + x4*2);
                            Wb[k*64 + x4*2]   = make_float2(tv.x*sk, -tv.y*sk);
                            Wb[k*64 + x4*2+1] = make_float2(tv.z*sk, -tv.w*sk);
                        }
                        __syncthreads();
                        #pragma unroll
                        for (int k = 0; k < 16; ++k) {
                            float2 av[8], bv[4];
                            #pragma unroll
                            for (int si = 0; si < 8; ++si) av[si] = Tb[k*128 + rq + 16*si];
                            #pragma unroll
                            for (int u = 0; u < 4; ++u) bv[u] = Wb[k*64 + cq + 16*u];
                            #pragma unroll
                            for (int si = 0; si < 8; ++si)
                                #pragma unroll
                                for (int u = 0; u < 4; ++u) {
                                    acc[si][u].x = fmaf(av[si].x, bv[u].x, fmaf(-av[si].y, bv[u].y, acc[si][u].x));
                                    acc[si][u].y = fmaf(av[si].x, bv[u].y, fmaf( av[si].y, bv[u].x, acc[si][u].y));
                                }
                        }
                    }
                    #pragma unroll
                    for (int si = 0; si < 8; ++si) {
                        float2* gp = G + (size_t)(ry + rq + 16*si) * BAP + cx + cq;
                        #pragma unroll
                        for (int u = 0; u < 4; ++u) {
                            float2 gg = gp[16*u];
                            gg.x -= acc[si][u].x;
                            gg.y -= acc[si][u].y;
                            gp[16*u] = gg;
                        }
                    }
                    __syncthreads();
                } else {
                    int d = wk - nct;
                    int j = d * 128 + (t & 127);
                    if (t < 128 && j < p0 + 64) {
                        float acc2 = 0.f;
                        for (int k = 0; k < 64; ++k) {
                            float2 tv = T[(size_t)k * BAP + j];
                            acc2 = fmaf(sarr[k], fmaf(tv.x, tv.x, tv.y*tv.y), acc2);
                        }
                        size_t jj2 = (size_t)j * BAP + j;
                        float2 g = G[jj2];
                        g.x -= acc2;
                        G[jj2] = g;
                    }
                }
            }
        }
        grid_barrier(bar);
    }
}

// ---------------- finalize ----------------
__global__ __launch_bounds__(256) void finalize_k(const float2* __restrict__ G, const float2* __restrict__ xd,
                                                  float* __restrict__ out, int out_size) {
    int o = blockIdx.x * 256 + threadIdx.x;
    if (o >= 2000) return;
    int b = o / 50, a = o % 50;
    int j = b * 50 + (49 - a);
    float2 x = xd[j];
    float2 g = G[(size_t)j * BAP + j];
    float den = 1.0f / (g.x*g.x + g.y*g.y);
    float re = (x.x*g.x + x.y*g.y) * den;
    float im = (x.y*g.x - x.x*g.y) * den;
    out[o] = re;
    if (out_size >= 4000) out[2000 + o] = im;
}

extern "C" void kernel_launch(void* const* d_in, const int* in_sizes, int n_in,
                              void* d_out, int out_size, void* d_ws, size_t ws_size,
                              hipStream_t stream) {
    const float* sar = (const float*)d_in[0];
    const int*   py  = (const int*)d_in[1];
    float* out = (float*)d_out;
    char* w = (char*)d_ws;
    size_t off = 0;
    auto take = [&](size_t sz) -> char* { char* p = w + off; off += (sz + 255) & ~(size_t)255; return p; };

    float*  R   = (float*)take((size_t)BAP*BAP*4);
    float*  Pm  = (float*)take((size_t)BAP*BAP*4);
    float2* G  = (float2*)take((size_t)BAP*BAP*8);
    float2* T  = (float2*)take((size_t)64*BAP*8);
    float2* xd = (float2*)take((size_t)BAP*8);
    float*  ay = (float*)take((size_t)KPADMAX*4);
    float*  ax = (float*)take((size_t)KPADMAX*4);
    float*  rd = (float*)take((size_t)KPADMAX*4);
    float2* Vp = (float2*)take(64*64*8);
    float2* vv   = (float2*)take(64*8);
    float*  sarr = (float*)take(64*4);
    int*    bar  = (int*)take(256);

    size_t avail = (ws_size > off + 4096) ? (ws_size - off - 4096) : 0;
    long long Kc = (long long)(avail / 8192) & ~2047LL;
    if (Kc > KPADMAX) Kc = KPADMAX;
    if (Kc < 2048) Kc = 2048;
    int nch = (int)((KKTOT + Kc - 1) / Kc);
    long long Kc2 = 2048LL * ((KKTOT + (long long)nch*2048 - 1) / ((long long)nch*2048));
    if (Kc2 >= 2048 && Kc2 <= Kc) Kc = Kc2;
    _Float16* C = (_Float16*)take((size_t)BAP * Kc * 2);
    _Float16* S = (_Float16*)take((size_t)BAP * Kc * 2);
    int kiters = (int)(Kc / 64);

    hipMemsetAsync(R, 0, (size_t)BAP*BAP*4*2, stream);  // R, Pm contiguous
    hipMemsetAsync(bar, 0, 256, stream);                // barrier count/gen = 0 (ws is poisoned)

    decode_k<<<dim3(391), dim3(256), 0, stream>>>(sar, py, ay, ax, rd);
    xd_init<<<dim3(BAP), dim3(256), 0, stream>>>(ay, ax, rd, xd);

    for (int c0 = 0; c0 < nch; ++c0) {
        gen_cs<<<dim3((unsigned)(Kc/2048), BAP), dim3(256), 0, stream>>>(C, S, ay, ax, (int)(c0*Kc), (int)Kc);
        gemm_ut<<<dim3(136, 16), dim3(256), 0, stream>>>(C, S, R, Pm, kiters, (int)Kc);
    }
    build_G_tile<<<dim3(32, 32), dim3(256), 0, stream>>>(R, Pm, G);

    // fused panel chain: normal launch, manual device-scope grid barrier
    chain_k<<<dim3(NBLK), dim3(256), 0, stream>>>(G, xd, T, Vp, vv, sarr, bar);

    finalize_k<<<dim3(8), dim3(256), 0, stream>>>(G, xd, out, out_size);
}